// Round 15
// baseline (699.209 us; speedup 1.0000x reference)
//
#include <hip/hip_runtime.h>
#include <math.h>

// DCGRU cell, N=8192. MEASUREMENT ROUND: R14 pipeline (286 us) + k_probe =
// hop1 body looped 8x into scratch, launched after k_build (same cache state
// as real hop1). Probe ~360us -> beats 155us poison-fills into top-5 WITH
// counters: per-hop steady-state time = probe_dur/8, MfmaUtil/VALUBusy/
// FETCH_SIZE/BANK_CONFLICT decide the next optimization branch.

typedef __attribute__((ext_vector_type(8))) short short8v;
typedef __attribute__((ext_vector_type(4))) float f32x4;

constexpr int NN  = 8192;
constexpr int CST = 80;
constexpr int KBT = 256;
constexpr int MCH = 4;
constexpr size_t NS   = (size_t)NN * CST;
constexpr size_t UTFS = (size_t)KBT * 5 * 512;

static __device__ __forceinline__ ushort f2bf(float x) {
  union { float f; unsigned u; } c; c.f = x;
  unsigned u = c.u;
  u += 0x7fffu + ((u >> 16) & 1u);               // RNE
  return (ushort)(u >> 16);
}

static __device__ __forceinline__ void mfma_b16(f32x4& acc, short8v a, short8v b) {
  asm("v_mfma_f32_16x16x32_bf16 %0, %1, %2, %0" : "+v"(acc) : "v"(a), "v"(b));
}

// ---------------- adj -> bf16 fragment transpose + row-sum partials ----------
__global__ __launch_bounds__(256, 4) void k_conv(const float* __restrict__ adj,
                                                 ushort* __restrict__ adjF,
                                                 float* __restrict__ dpart) {
  __shared__ float tile[2][32][132];
  const int kb = blockIdx.x, mc = blockIdx.y;
  const int tid = threadIdx.x;
  const int l = tid & 63, w = tid >> 6;
  const int rg = tid >> 5;
  const int cb = (tid & 31) * 4;
  const float* src = adj + ((size_t)kb * 32 + rg) * NN + (size_t)mc * 2048 + cb;
  float rs[4] = {0.f, 0.f, 0.f, 0.f};
  float4 vA[4], vB[4];

#pragma unroll
  for (int i = 0; i < 4; ++i)
    vA[i] = *(const float4*)(src + (size_t)(8 * i) * NN);

#define CONV_BODY(CH, BUF, VC, VN)                                             \
  {                                                                            \
    const int ch_ = (CH);                                                      \
    _Pragma("unroll") for (int i = 0; i < 4; ++i) {                            \
      int r = rg + 8 * i;                                                      \
      int colp = (cb + 8 * i) & 127;                                           \
      *(float4*)&tile[BUF][r][colp] = VC[i];                                   \
      rs[i] += (VC[i].x + VC[i].y) + (VC[i].z + VC[i].w);                      \
    }                                                                          \
    if (ch_ < 15) {                                                            \
      _Pragma("unroll") for (int i = 0; i < 4; ++i)                            \
          VN[i] = *(const float4*)(src + (size_t)(8 * i) * NN + (ch_ + 1) * 128); \
    }                                                                          \
    __syncthreads();                                                           \
    _Pragma("unroll") for (int h = 0; h < 2; ++h) {                            \
      int fl = w + 4 * h;                                                      \
      int mt = mc * 128 + ch_ * 8 + fl;                                        \
      short8v o;                                                               \
      _Pragma("unroll") for (int j = 0; j < 8; ++j) {                          \
        int r = 8 * (l >> 4) + j;                                              \
        int colp = (fl * 16 + (l & 15) + 8 * (l >> 4)) & 127;                  \
        o[j] = (short)f2bf(tile[BUF][r][colp]);                                \
      }                                                                        \
      *(short8v*)(adjF + ((size_t)mt * KBT + kb) * 512 + l * 8) = o;           \
    }                                                                          \
  }

  for (int cp = 0; cp < 8; ++cp) {
    CONV_BODY(2 * cp,     0, vA, vB);
    CONV_BODY(2 * cp + 1, 1, vB, vA);
  }
#undef CONV_BODY

#pragma unroll
  for (int i = 0; i < 4; ++i) {
#pragma unroll
    for (int m = 16; m >= 1; m >>= 1) rs[i] += __shfl_xor(rs[i], m);
  }
  if ((tid & 31) == 0) {
#pragma unroll
    for (int i = 0; i < 4; ++i)
      dpart[(size_t)mc * NN + kb * 32 + 8 * i + rg] = rs[i];
  }
}

// ---------------- build: dinv + X0 + XS0 + UtFa ------------------------------
__global__ __launch_bounds__(256) void k_build(const float* __restrict__ hx,
                                               const float* __restrict__ inp,
                                               const float* __restrict__ dpart,
                                               float* __restrict__ dinv,
                                               float* __restrict__ X0,
                                               float* __restrict__ XS0,
                                               ushort* __restrict__ UtF) {
  __shared__ float dv_s[32];
  const int n0 = blockIdx.x * 32;
  const int tid = threadIdx.x;
  if (tid < 32) {
    int n = n0 + tid;
    float dv = 1.f / (dpart[n] + dpart[NN + n] + dpart[2 * NN + n] +
                      dpart[3 * NN + n] + 1.f);
    dv_s[tid] = dv;
    dinv[n] = dv;
  }
  __syncthreads();
  for (int p = tid; p < 32 * 20; p += 256) {
    int nl = p / 20, c4 = (p % 20) * 4;
    int n = n0 + nl;
    float dv = dv_s[nl];
    float v[4];
#pragma unroll
    for (int j = 0; j < 4; ++j) {
      int c = c4 + j;
      v[j] = (c < 64) ? hx[n * 64 + c] : (c < 66 ? inp[n * 2 + (c - 64)] : 0.f);
    }
    size_t o = (size_t)n * CST + c4;
    *(float4*)(X0 + o)  = make_float4(v[0], v[1], v[2], v[3]);
    *(float4*)(XS0 + o) = make_float4(dv * v[0], dv * v[1], dv * v[2], dv * v[3]);
  }
  for (int p = tid; p < 5 * 64; p += 256) {
    int nt = p >> 6, l = p & 63;
    short8v o8;
#pragma unroll
    for (int j = 0; j < 8; ++j) {
      int nloc = 8 * (l >> 4) + j;
      int n = n0 + nloc;
      int c = nt * 16 + (l & 15);
      float v = (c < 64) ? hx[n * 64 + c] : (c < 66 ? inp[n * 2 + (c - 64)] : 0.f);
      o8[j] = (short)f2bf(v * dv_s[nloc]);
    }
    *(short8v*)(UtF + ((size_t)blockIdx.x * 5 + nt) * 512 + l * 8) = o8;
  }
}

// ---------------- GEMM core: 8-wave K-split, 2 mt per wave, shared B ---------
static __device__ __forceinline__ void gemm_core2(const ushort* __restrict__ adjF,
                                                  const ushort* __restrict__ bF,
                                                  int bid, int tid, float* smem,
                                                  float sv[5]) {
  const int w8 = tid >> 6, l = tid & 63;
  const int kbase = w8 * 32;
  f32x4 acc0[5], acc1[5];
#pragma unroll
  for (int nt = 0; nt < 5; ++nt) {
    acc0[nt] = (f32x4){0.f, 0.f, 0.f, 0.f};
    acc1[nt] = (f32x4){0.f, 0.f, 0.f, 0.f};
  }
  const ushort* ap = adjF + ((size_t)(2 * bid) * KBT + kbase) * 512 + l * 8;
  const size_t MSTR = (size_t)KBT * 512;          // adjF stride between mt
  const ushort* bp = bF + (size_t)kbase * 5 * 512 + l * 8;

  short8v aE0, aE1, aO0, aO1, bE[5], bO[5];
  aE0 = *(const short8v*)(ap);
  aE1 = *(const short8v*)(ap + MSTR);
#pragma unroll
  for (int nt = 0; nt < 5; ++nt) bE[nt] = *(const short8v*)(bp + nt * 512);

  for (int kb = 0; kb < 32; kb += 2) {
    aO0 = *(const short8v*)(ap + (size_t)(kb + 1) * 512);
    aO1 = *(const short8v*)(ap + MSTR + (size_t)(kb + 1) * 512);
#pragma unroll
    for (int nt = 0; nt < 5; ++nt)
      bO[nt] = *(const short8v*)(bp + (size_t)((kb + 1) * 5 + nt) * 512);
#pragma unroll
    for (int nt = 0; nt < 5; ++nt) {
      mfma_b16(acc0[nt], aE0, bE[nt]);
      mfma_b16(acc1[nt], aE1, bE[nt]);
    }
    aE0 = *(const short8v*)(ap + (size_t)(kb + 2) * 512);
    aE1 = *(const short8v*)(ap + MSTR + (size_t)(kb + 2) * 512);
#pragma unroll
    for (int nt = 0; nt < 5; ++nt)
      bE[nt] = *(const short8v*)(bp + (size_t)((kb + 2) * 5 + nt) * 512);
#pragma unroll
    for (int nt = 0; nt < 5; ++nt) {
      mfma_b16(acc0[nt], aO0, bO[nt]);
      mfma_b16(acc1[nt], aO1, bO[nt]);
    }
  }
  asm volatile("s_nop 7\n\ts_nop 7\n\ts_nop 7" ::: "memory");

  auto red = reinterpret_cast<float(*)[64][40]>(smem);    // [4][64][40] = 40 KB
  if (w8 < 4) {
#pragma unroll
    for (int nt = 0; nt < 5; ++nt) {
      *(f32x4*)&red[w8][l][nt * 4]      = acc0[nt];
      *(f32x4*)&red[w8][l][20 + nt * 4] = acc1[nt];
    }
  }
  __syncthreads();
  if (w8 >= 4) {
#pragma unroll
    for (int nt = 0; nt < 5; ++nt) {
      f32x4 t0 = *(f32x4*)&red[w8 - 4][l][nt * 4];
      f32x4 t1 = *(f32x4*)&red[w8 - 4][l][20 + nt * 4];
      *(f32x4*)&red[w8 - 4][l][nt * 4]      = t0 + acc0[nt];
      *(f32x4*)&red[w8 - 4][l][20 + nt * 4] = t1 + acc1[nt];
    }
  }
  __syncthreads();
#pragma unroll
  for (int i = 0; i < 5; ++i) {
    int p = tid + i * 512;
    int r = p / 80, c = p % 80;
    int mtl = r >> 4, rl = r & 15;
    int ll = ((rl >> 2) << 4) | (c & 15);
    int slot = mtl * 20 + (((c >> 4) << 2) | (rl & 3));
    sv[i] = ((red[0][ll][slot] + red[1][ll][slot]) +
             red[2][ll][slot]) + red[3][ll][slot];
  }
  __syncthreads();                                        // smem reusable
}

// ---------------- PROBE: hop1 body x8 into scratch (idempotent) --------------
__global__ __launch_bounds__(512, 1) void k_probe(const ushort* __restrict__ adjF,
                                                  const ushort* __restrict__ UtFin,
                                                  const float* __restrict__ XSin,
                                                  const float* __restrict__ dinv,
                                                  float* __restrict__ X1p,
                                                  float* __restrict__ XS1p,
                                                  ushort* __restrict__ UtFp) {
  __shared__ __align__(16) float smem[10240];
  const int bid = blockIdx.x, tid = threadIdx.x;
  const int n0 = bid * 32;
#pragma unroll 1
  for (int it = 0; it < 8; ++it) {
    float sv[5];
    gemm_core2(adjF, UtFin, bid, tid, smem, sv);
    auto xs = reinterpret_cast<float(*)[80]>(smem);
#pragma unroll
    for (int i = 0; i < 5; ++i) {
      int p = tid + i * 512;
      size_t o = (size_t)n0 * CST + p;
      float x1 = XSin[o] + sv[i];
      X1p[o] = x1;
      float z = dinv[n0 + p / 80] * x1;
      XS1p[o] = z;
      xs[p / 80][p % 80] = z;
    }
    __syncthreads();
    for (int p = tid; p < 5 * 64; p += 512) {
      int nt = p >> 6, l = p & 63;
      short8v o8;
#pragma unroll
      for (int j = 0; j < 8; ++j)
        o8[j] = (short)f2bf(xs[8 * (l >> 4) + j][nt * 16 + (l & 15)]);
      *(short8v*)(UtFp + ((size_t)bid * 5 + nt) * 512 + l * 8) = o8;
    }
    __syncthreads();
  }
}

// ---------------- hop1: X1 = A^T@XSin + XSin ; XS1 = dinv*X1 ; UtFout --------
__global__ __launch_bounds__(512, 1) void k_hop1(const ushort* __restrict__ adjF,
                                                 const ushort* __restrict__ UtFin,
                                                 const float* __restrict__ XSin,
                                                 const float* __restrict__ dinv,
                                                 float* __restrict__ X1,
                                                 float* __restrict__ XS1,
                                                 ushort* __restrict__ UtFout) {
  __shared__ __align__(16) float smem[10240];
  const int bid = blockIdx.x, tid = threadIdx.x;
  const int n0 = bid * 32;
  float sv[5];
  gemm_core2(adjF, UtFin, bid, tid, smem, sv);

  auto xs = reinterpret_cast<float(*)[80]>(smem);
#pragma unroll
  for (int i = 0; i < 5; ++i) {
    int p = tid + i * 512;
    size_t o = (size_t)n0 * CST + p;
    float x1 = XSin[o] + sv[i];
    X1[o] = x1;
    float z = dinv[n0 + p / 80] * x1;
    XS1[o] = z;
    xs[p / 80][p % 80] = z;
  }
  __syncthreads();
  for (int p = tid; p < 5 * 64; p += 512) {
    int nt = p >> 6, l = p & 63;
    short8v o8;
#pragma unroll
    for (int j = 0; j < 8; ++j)
      o8[j] = (short)f2bf(xs[8 * (l >> 4) + j][nt * 16 + (l & 15)]);
    *(short8v*)(UtFout + ((size_t)bid * 5 + nt) * 512 + l * 8) = o8;
  }
}

// ---------------- hop2+gates: X2 in LDS; sigmoid matmul; X0:=rh etc. ---------
__global__ __launch_bounds__(512, 1) void k_hop2g(const ushort* __restrict__ adjF,
    const ushort* __restrict__ UtFb, const float* __restrict__ XS1,
    const float* __restrict__ X0, const float* __restrict__ X1,
    const float* __restrict__ w_ru, const float* __restrict__ b_ru,
    const float* __restrict__ hx, const float* __restrict__ inp,
    const float* __restrict__ dinv,
    float* __restrict__ X0w, float* __restrict__ XS0w,
    ushort* __restrict__ UtFa, float* __restrict__ UG) {
  __shared__ __align__(16) float smem[10240];
  const int bid = blockIdx.x, tid = threadIdx.x;
  const int n0 = bid * 32;
  float sv[5];
  gemm_core2(adjF, UtFb, bid, tid, smem, sv);

  auto xr2 = reinterpret_cast<float(*)[80]>(smem);        // [32][80] = 2560
  float* xr01 = smem + 2560;                              // [2][32][68] = 4352
  float* rhq  = smem + 2560 + 4352;                       // [32][64] = 2048
#pragma unroll
  for (int i = 0; i < 5; ++i) {
    int p = tid + i * 512;
    size_t o = (size_t)n0 * CST + p;
    xr2[p / 80][p % 80] = 2.f * (XS1[o] + sv[i]) - X0[o];
  }
  for (int p = tid; p < 32 * 17; p += 512) {
    int nl = p / 17, c4 = (p % 17) * 4;
    size_t o = (size_t)(n0 + nl) * CST + c4;
    *(float4*)&xr01[nl * 68 + c4]            = *(const float4*)(X0 + o);
    *(float4*)&xr01[32 * 68 + nl * 68 + c4]  = *(const float4*)(X1 + o);
  }
  __syncthreads();

  const int nl = tid >> 4, og = tid & 15, o0 = og * 8;
  float acc[8];
#pragma unroll
  for (int j = 0; j < 8; ++j) acc[j] = b_ru[o0 + j];
  for (int c = 0; c < 66; ++c) {
    int f = (c < 64) ? (c + 2) : (c - 64);
    const float* wr = w_ru + (size_t)(f * 3) * 128 + o0;
    float xv[3];
    xv[0] = xr01[nl * 68 + c];
    xv[1] = xr01[32 * 68 + nl * 68 + c];
    xv[2] = xr2[nl][c];
#pragma unroll
    for (int m = 0; m < 3; ++m) {
      float wl[8];
      *(float4*)(wl)     = *(const float4*)(wr + m * 128);
      *(float4*)(wl + 4) = *(const float4*)(wr + m * 128 + 4);
#pragma unroll
      for (int j = 0; j < 8; ++j) acc[j] += xv[m] * wl[j];
    }
  }
  const int n = n0 + nl;
  const float dv = dinv[n];
  if (og < 8) {
#pragma unroll
    for (int j = 0; j < 8; ++j) {
      int o = o0 + j;
      float r = 1.f / (1.f + expf(-acc[j]));
      float rh = r * hx[n * 64 + o];
      X0w[(size_t)n * CST + o] = rh;
      float srh = dv * rh;
      XS0w[(size_t)n * CST + o] = srh;
      rhq[nl * 64 + o] = srh;
    }
  } else {
#pragma unroll
    for (int j = 0; j < 8; ++j)
      UG[n * 64 + (o0 - 64) + j] = 1.f / (1.f + expf(-acc[j]));
  }
  __syncthreads();
  for (int p = tid; p < 5 * 64; p += 512) {
    int nt = p >> 6, l = p & 63;
    short8v o8;
#pragma unroll
    for (int j = 0; j < 8; ++j) {
      int lr = 8 * (l >> 4) + j;
      int nn = n0 + lr;
      int c = nt * 16 + (l & 15);
      float v;
      if (c < 64)      v = rhq[lr * 64 + c];
      else if (c < 66) v = dinv[nn] * inp[nn * 2 + (c - 64)];
      else             v = 0.f;
      o8[j] = (short)f2bf(v);
    }
    *(short8v*)(UtFa + ((size_t)bid * 5 + nt) * 512 + l * 8) = o8;
  }
}

// ---------------- hop2+final: X2 in LDS; tanh matmul; output -----------------
__global__ __launch_bounds__(512, 1) void k_hop2f(const ushort* __restrict__ adjF,
    const ushort* __restrict__ UtFb, const float* __restrict__ XS1,
    const float* __restrict__ X0, const float* __restrict__ X1,
    const float* __restrict__ w_c, const float* __restrict__ b_c,
    const float* __restrict__ hx, const float* __restrict__ UG,
    float* __restrict__ out) {
  __shared__ __align__(16) float smem[10240];
  const int bid = blockIdx.x, tid = threadIdx.x;
  const int n0 = bid * 32;
  float sv[5];
  gemm_core2(adjF, UtFb, bid, tid, smem, sv);

  auto xr2 = reinterpret_cast<float(*)[80]>(smem);        // [32][80]
  float* xr01 = smem + 2560;                              // [2][32][68]
#pragma unroll
  for (int i = 0; i < 5; ++i) {
    int p = tid + i * 512;
    size_t o = (size_t)n0 * CST + p;
    xr2[p / 80][p % 80] = 2.f * (XS1[o] + sv[i]) - X0[o];
  }
  for (int p = tid; p < 32 * 17; p += 512) {
    int nl = p / 17, c4 = (p % 17) * 4;
    size_t o = (size_t)(n0 + nl) * CST + c4;
    *(float4*)&xr01[nl * 68 + c4]           = *(const float4*)(X0 + o);
    *(float4*)&xr01[32 * 68 + nl * 68 + c4] = *(const float4*)(X1 + o);
  }
  __syncthreads();

  const int nl = tid >> 4, ot = tid & 15, o0 = ot * 4;
  float acc[4];
#pragma unroll
  for (int j = 0; j < 4; ++j) acc[j] = b_c[o0 + j];
  for (int c = 0; c < 66; ++c) {
    int f = (c < 64) ? (c + 2) : (c - 64);
    float xv[3];
    xv[0] = xr01[nl * 68 + c];
    xv[1] = xr01[32 * 68 + nl * 68 + c];
    xv[2] = xr2[nl][c];
#pragma unroll
    for (int m = 0; m < 3; ++m) {
      float wl[4];
      *(float4*)(wl) = *(const float4*)(w_c + (size_t)(f * 3 + m) * 64 + o0);
#pragma unroll
      for (int j = 0; j < 4; ++j) acc[j] += xv[m] * wl[j];
    }
  }
  const int n = n0 + nl;
#pragma unroll
  for (int j = 0; j < 4; ++j) {
    int o = o0 + j;
    float cc = tanhf(acc[j]);
    float u = UG[n * 64 + o];
    float h = hx[n * 64 + o];
    out[n * 64 + o] = u * h + (1.f - u) * cc;
  }
}

// ---------------- launcher ----------------------------------------------------
extern "C" void kernel_launch(void* const* d_in, const int* in_sizes, int n_in,
                              void* d_out, int out_size, void* d_ws, size_t ws_size,
                              hipStream_t stream) {
  const float* inp  = (const float*)d_in[0];
  const float* hx   = (const float*)d_in[1];
  const float* adj  = (const float*)d_in[2];
  const float* w_ru = (const float*)d_in[3];
  const float* b_ru = (const float*)d_in[4];
  const float* w_c  = (const float*)d_in[5];
  const float* b_c  = (const float*)d_in[6];
  float* out = (float*)d_out;

  float* ws    = (float*)d_ws;
  float* dinv  = ws;                          // 8192
  float* dpart = ws + 8192;                   // 4*8192
  float* X0    = ws + 8192 + 4 * 8192;        // [N][80] each
  float* XS0   = X0 + NS;
  float* X1    = XS0 + NS;
  float* XS1   = X1 + NS;
  ushort* UtFa = (ushort*)(XS1 + NS);         // 1.25 MB
  ushort* UtFb = UtFa + UTFS;                 // 1.25 MB
  ushort* adjF = UtFb + UTFS;                 // 128 MB
  float*  UG   = (float*)(adjF + (size_t)512 * KBT * 512);  // [N][64] + OOB pad
  float*  X1p  = UG + (size_t)NN * 64;        // probe scratch
  float*  XS1p = X1p + NS;
  ushort* UtFp = (ushort*)(XS1p + NS);

  dim3 cg(KBT, MCH);

  k_conv <<<cg, 256, 0, stream>>>(adj, adjF, dpart);
  k_build<<<NN / 32, 256, 0, stream>>>(hx, inp, dpart, dinv, X0, XS0, UtFa);

  // PROBE: 8x hop1 into scratch — top-1 dispatch with real counters.
  k_probe<<<256, 512, 0, stream>>>(adjF, UtFa, XS0, dinv, X1p, XS1p, UtFp);

  // gconv 1 (gates)
  k_hop1 <<<256, 512, 0, stream>>>(adjF, UtFa, XS0, dinv, X1, XS1, UtFb);
  k_hop2g<<<256, 512, 0, stream>>>(adjF, UtFb, XS1, X0, X1, w_ru, b_ru, hx, inp,
                                   dinv, X0, XS0, UtFa, UG);

  // gconv 2 (candidate)
  k_hop1 <<<256, 512, 0, stream>>>(adjF, UtFa, XS0, dinv, X1, XS1, UtFb);
  k_hop2f<<<256, 512, 0, stream>>>(adjF, UtFb, XS1, X0, X1, w_c, b_c, hx, UG, out);
}

// Round 16
// 228.492 us; speedup vs baseline: 3.0601x; 3.0601x over previous
//
#include <hip/hip_runtime.h>
#include <math.h>

// DCGRU cell, N=8192, B=1, D_IN=2, UNITS=64, K=2 -> F=66, M=3.
// adj_mx @ v == adj^T @ (dinv*v) + (dinv*v)   (adj2 = adj + I folded in)
// 6 launches: k_conv -> k_build -> k_hop1 -> k_hop2g -> k_hop1 -> k_hop2f
// GEMM operands in FP8-E4M3 (v_mfma_f32_16x16x32_fp8_fp8, f32 accum):
//   adjF8: 64 MB, superfrag-paired: (mt, sf) 1KB block, lane l byte
//     half*8+j = adj[(2sf+half)*32 + 8*(l>>4)+j][mt*16+(l&15)]  (raw adj, no scale)
//   UtF8: B fragments scaled by SC (power of 2), same pairing; epilogue
//     multiplies GEMM result by 1/SC (exact).
// Each 16B/lane load feeds 2 MFMAs (request count halved vs bf16).
// Identical (l,j)->k packing on A and B keeps the dot product permutation-safe.

typedef __attribute__((ext_vector_type(4))) float f32x4;
typedef __attribute__((ext_vector_type(2))) int v2i;
typedef __attribute__((ext_vector_type(4))) int v4i;
typedef unsigned char uch;

constexpr int NN  = 8192;
constexpr int CST = 80;
constexpr int KBT = 256;                     // k-blocks of 32
constexpr int SFT = KBT / 2;                 // 128 superfrags
constexpr int MCH = 4;
constexpr size_t NS    = (size_t)NN * CST;
constexpr size_t UTFS8 = (size_t)SFT * 5 * 1024;    // bytes per UtF8 buffer

constexpr float SC1  = 4096.f,   ISC1 = 1.f / 4096.f;     // hop1 B scale (2^12)
constexpr float SC2  = 262144.f, ISC2 = 1.f / 262144.f;   // hop2 B scale (2^18)

static __device__ __forceinline__ unsigned f2e4m3(float x) {
  union { float f; unsigned u; } c; c.f = x;
  unsigned s = (c.u >> 24) & 0x80u;
  float a = fabsf(x);
  if (a >= 464.f) return s | 0x7Eu;          // saturate to 448 (avoid NaN 0x7F)
  if (a < 0.015625f) {                       // subnormal: q = round(a * 2^9)
    int q = (int)(a * 512.f + 0.5f);         // q in [0,8]; 8 -> min normal
    return s | (unsigned)q;
  }
  c.f = a;
  unsigned u = c.u + (0x7FFFFu + ((c.u >> 20) & 1u));     // RNE to 3 mant bits
  int e = (int)((u >> 23) & 0xFFu) - 127;
  unsigned m = (u >> 20) & 7u;
  if (e > 8) return s | 0x7Eu;
  return s | (unsigned)(((e + 7) << 3) | m);
}

static __device__ __forceinline__ void mfma_f8(f32x4& acc, v2i a, v2i b) {
  asm("v_mfma_f32_16x16x32_fp8_fp8 %0, %1, %2, %0" : "+v"(acc) : "v"(a), "v"(b));
}
static __device__ __forceinline__ v2i lo2(v4i v) { v2i r; r.x = v.x; r.y = v.y; return r; }
static __device__ __forceinline__ v2i hi2(v4i v) { v2i r; r.x = v.z; r.y = v.w; return r; }

// ---------------- adj -> fp8 superfrag transpose + row-sum partials ----------
__global__ __launch_bounds__(256, 4) void k_conv(const float* __restrict__ adj,
                                                 uch* __restrict__ adjF8,
                                                 float* __restrict__ dpart) {
  __shared__ float tile[2][32][132];
  const int kb = blockIdx.x, mc = blockIdx.y;
  const int tid = threadIdx.x;
  const int l = tid & 63, w = tid >> 6;
  const int rg = tid >> 5;
  const int cb = (tid & 31) * 4;
  const float* src = adj + ((size_t)kb * 32 + rg) * NN + (size_t)mc * 2048 + cb;
  float rs[4] = {0.f, 0.f, 0.f, 0.f};
  float4 vA[4], vB[4];

#pragma unroll
  for (int i = 0; i < 4; ++i)
    vA[i] = *(const float4*)(src + (size_t)(8 * i) * NN);

#define CONV_BODY(CH, BUF, VC, VN)                                             \
  {                                                                            \
    const int ch_ = (CH);                                                      \
    _Pragma("unroll") for (int i = 0; i < 4; ++i) {                            \
      int r = rg + 8 * i;                                                      \
      int colp = (cb + 8 * i) & 127;                                           \
      *(float4*)&tile[BUF][r][colp] = VC[i];                                   \
      rs[i] += (VC[i].x + VC[i].y) + (VC[i].z + VC[i].w);                      \
    }                                                                          \
    if (ch_ < 15) {                                                            \
      _Pragma("unroll") for (int i = 0; i < 4; ++i)                            \
          VN[i] = *(const float4*)(src + (size_t)(8 * i) * NN + (ch_ + 1) * 128); \
    }                                                                          \
    __syncthreads();                                                           \
    _Pragma("unroll") for (int h = 0; h < 2; ++h) {                            \
      int fl = w + 4 * h;                                                      \
      int mt = mc * 128 + ch_ * 8 + fl;                                        \
      int colp = (fl * 16 + (l & 15) + 8 * (l >> 4)) & 127;                    \
      unsigned plo = 0, phi = 0;                                               \
      _Pragma("unroll") for (int j = 0; j < 4; ++j)                            \
        plo |= f2e4m3(tile[BUF][8 * (l >> 4) + j][colp]) << (8 * j);           \
      _Pragma("unroll") for (int j = 4; j < 8; ++j)                            \
        phi |= f2e4m3(tile[BUF][8 * (l >> 4) + j][colp]) << (8 * (j - 4));     \
      uint2 pk; pk.x = plo; pk.y = phi;                                        \
      *(uint2*)(adjF8 + ((size_t)mt * SFT + (kb >> 1)) * 1024                  \
                + l * 16 + (kb & 1) * 8) = pk;                                 \
    }                                                                          \
  }

  for (int cp = 0; cp < 8; ++cp) {
    CONV_BODY(2 * cp,     0, vA, vB);
    CONV_BODY(2 * cp + 1, 1, vB, vA);
  }
#undef CONV_BODY

#pragma unroll
  for (int i = 0; i < 4; ++i) {
#pragma unroll
    for (int m = 16; m >= 1; m >>= 1) rs[i] += __shfl_xor(rs[i], m);
  }
  if ((tid & 31) == 0) {
#pragma unroll
    for (int i = 0; i < 4; ++i)
      dpart[(size_t)mc * NN + kb * 32 + 8 * i + rg] = rs[i];
  }
}

// ---------------- build: dinv + X0 + XS0 + UtFa8 -----------------------------
__global__ __launch_bounds__(256) void k_build(const float* __restrict__ hx,
                                               const float* __restrict__ inp,
                                               const float* __restrict__ dpart,
                                               float* __restrict__ dinv,
                                               float* __restrict__ X0,
                                               float* __restrict__ XS0,
                                               uch* __restrict__ UtF8) {
  __shared__ float dv_s[32];
  const int bid = blockIdx.x;
  const int n0 = bid * 32;
  const int tid = threadIdx.x;
  if (tid < 32) {
    int n = n0 + tid;
    float dv = 1.f / (dpart[n] + dpart[NN + n] + dpart[2 * NN + n] +
                      dpart[3 * NN + n] + 1.f);
    dv_s[tid] = dv;
    dinv[n] = dv;
  }
  __syncthreads();
  for (int p = tid; p < 32 * 20; p += 256) {
    int nl = p / 20, c4 = (p % 20) * 4;
    int n = n0 + nl;
    float dv = dv_s[nl];
    float v[4];
#pragma unroll
    for (int j = 0; j < 4; ++j) {
      int c = c4 + j;
      v[j] = (c < 64) ? hx[n * 64 + c] : (c < 66 ? inp[n * 2 + (c - 64)] : 0.f);
    }
    size_t o = (size_t)n * CST + c4;
    *(float4*)(X0 + o)  = make_float4(v[0], v[1], v[2], v[3]);
    *(float4*)(XS0 + o) = make_float4(dv * v[0], dv * v[1], dv * v[2], dv * v[3]);
  }
  for (int p = tid; p < 5 * 64; p += 256) {
    int nt = p >> 6, l = p & 63;
    unsigned plo = 0, phi = 0;
#pragma unroll
    for (int j = 0; j < 8; ++j) {
      int nloc = 8 * (l >> 4) + j;
      int n = n0 + nloc;
      int c = nt * 16 + (l & 15);
      float v = (c < 64) ? hx[n * 64 + c] : (c < 66 ? inp[n * 2 + (c - 64)] : 0.f);
      unsigned b = f2e4m3(v * dv_s[nloc] * SC1);
      if (j < 4) plo |= b << (8 * j); else phi |= b << (8 * (j - 4));
    }
    uint2 pk; pk.x = plo; pk.y = phi;
    *(uint2*)(UtF8 + ((size_t)(bid >> 1) * 5 + nt) * 1024 + l * 16 + (bid & 1) * 8) = pk;
  }
}

// ---------------- GEMM core: fp8, 8-wave K-split, 2 mt/wave, shared B --------
// Leaves sv[i] = (full-K dot) * inv_scale for item p = tid + i*512 (32x80 tile).
static __device__ __forceinline__ void gemm_core2(const uch* __restrict__ adjF8,
                                                  const uch* __restrict__ bF8,
                                                  int bid, int tid, float* smem,
                                                  float sv[5], float inv_scale) {
  const int w8 = tid >> 6, l = tid & 63;
  const int sf0 = w8 * 16;                       // 16 superfrags (32 kb) per wave
  f32x4 acc0[5], acc1[5];
#pragma unroll
  for (int nt = 0; nt < 5; ++nt) {
    acc0[nt] = (f32x4){0.f, 0.f, 0.f, 0.f};
    acc1[nt] = (f32x4){0.f, 0.f, 0.f, 0.f};
  }
  const uch* ap = adjF8 + ((size_t)(2 * bid) * SFT + sf0) * 1024 + l * 16;
  const size_t MSTR = (size_t)SFT * 1024;
  const uch* bp = bF8 + (size_t)sf0 * 5 * 1024 + l * 16;

  v4i A0e, A1e, A0o, A1o, Be[5], Bo[5];
  A0e = *(const v4i*)(ap);
  A1e = *(const v4i*)(ap + MSTR);
#pragma unroll
  for (int nt = 0; nt < 5; ++nt) Be[nt] = *(const v4i*)(bp + nt * 1024);

  for (int sf = 0; sf < 16; sf += 2) {
    A0o = *(const v4i*)(ap + (size_t)(sf + 1) * 1024);
    A1o = *(const v4i*)(ap + MSTR + (size_t)(sf + 1) * 1024);
#pragma unroll
    for (int nt = 0; nt < 5; ++nt)
      Bo[nt] = *(const v4i*)(bp + (size_t)((sf + 1) * 5 + nt) * 1024);
#pragma unroll
    for (int nt = 0; nt < 5; ++nt) {
      mfma_f8(acc0[nt], lo2(A0e), lo2(Be[nt]));
      mfma_f8(acc1[nt], lo2(A1e), lo2(Be[nt]));
    }
#pragma unroll
    for (int nt = 0; nt < 5; ++nt) {
      mfma_f8(acc0[nt], hi2(A0e), hi2(Be[nt]));
      mfma_f8(acc1[nt], hi2(A1e), hi2(Be[nt]));
    }
    A0e = *(const v4i*)(ap + (size_t)(sf + 2) * 1024);
    A1e = *(const v4i*)(ap + MSTR + (size_t)(sf + 2) * 1024);
#pragma unroll
    for (int nt = 0; nt < 5; ++nt)
      Be[nt] = *(const v4i*)(bp + (size_t)((sf + 2) * 5 + nt) * 1024);
#pragma unroll
    for (int nt = 0; nt < 5; ++nt) {
      mfma_f8(acc0[nt], lo2(A0o), lo2(Bo[nt]));
      mfma_f8(acc1[nt], lo2(A1o), lo2(Bo[nt]));
    }
#pragma unroll
    for (int nt = 0; nt < 5; ++nt) {
      mfma_f8(acc0[nt], hi2(A0o), hi2(Bo[nt]));
      mfma_f8(acc1[nt], hi2(A1o), hi2(Bo[nt]));
    }
  }
  asm volatile("s_nop 7\n\ts_nop 7\n\ts_nop 7" ::: "memory");

  // two-stage reduce: waves 4-7 fold into waves 0-3, then 4-way sum.
  auto red = reinterpret_cast<float(*)[64][40]>(smem);    // [4][64][40] = 40 KB
  if (w8 < 4) {
#pragma unroll
    for (int nt = 0; nt < 5; ++nt) {
      *(f32x4*)&red[w8][l][nt * 4]      = acc0[nt];
      *(f32x4*)&red[w8][l][20 + nt * 4] = acc1[nt];
    }
  }
  __syncthreads();
  if (w8 >= 4) {
#pragma unroll
    for (int nt = 0; nt < 5; ++nt) {
      f32x4 t0 = *(f32x4*)&red[w8 - 4][l][nt * 4];
      f32x4 t1 = *(f32x4*)&red[w8 - 4][l][20 + nt * 4];
      *(f32x4*)&red[w8 - 4][l][nt * 4]      = t0 + acc0[nt];
      *(f32x4*)&red[w8 - 4][l][20 + nt * 4] = t1 + acc1[nt];
    }
  }
  __syncthreads();
#pragma unroll
  for (int i = 0; i < 5; ++i) {
    int p = tid + i * 512;
    int r = p / 80, c = p % 80;
    int mtl = r >> 4, rl = r & 15;
    int ll = ((rl >> 2) << 4) | (c & 15);
    int slot = mtl * 20 + (((c >> 4) << 2) | (rl & 3));
    sv[i] = (((red[0][ll][slot] + red[1][ll][slot]) +
              red[2][ll][slot]) + red[3][ll][slot]) * inv_scale;
  }
  __syncthreads();                                        // smem reusable
}

// ---------------- hop1: X1 = A^T@XSin + XSin ; XS1 = dinv*X1 ; UtFout --------
__global__ __launch_bounds__(512, 1) void k_hop1(const uch* __restrict__ adjF8,
                                                 const uch* __restrict__ UtFin,
                                                 const float* __restrict__ XSin,
                                                 const float* __restrict__ dinv,
                                                 float* __restrict__ X1,
                                                 float* __restrict__ XS1,
                                                 uch* __restrict__ UtFout) {
  __shared__ __align__(16) float smem[10240];
  const int bid = blockIdx.x, tid = threadIdx.x;
  const int n0 = bid * 32;
  float sv[5];
  gemm_core2(adjF8, UtFin, bid, tid, smem, sv, ISC1);

  auto xs = reinterpret_cast<float(*)[80]>(smem);
#pragma unroll
  for (int i = 0; i < 5; ++i) {
    int p = tid + i * 512;
    size_t o = (size_t)n0 * CST + p;
    float x1 = XSin[o] + sv[i];
    X1[o] = x1;
    float z = dinv[n0 + p / 80] * x1;
    XS1[o] = z;
    xs[p / 80][p % 80] = z;
  }
  __syncthreads();
  for (int p = tid; p < 5 * 64; p += 512) {
    int nt = p >> 6, l = p & 63;
    unsigned plo = 0, phi = 0;
#pragma unroll
    for (int j = 0; j < 8; ++j) {
      unsigned b = f2e4m3(xs[8 * (l >> 4) + j][nt * 16 + (l & 15)] * SC2);
      if (j < 4) plo |= b << (8 * j); else phi |= b << (8 * (j - 4));
    }
    uint2 pk; pk.x = plo; pk.y = phi;
    *(uint2*)(UtFout + ((size_t)(bid >> 1) * 5 + nt) * 1024 + l * 16 + (bid & 1) * 8) = pk;
  }
}

// ---------------- hop2+gates: X2 in LDS; sigmoid matmul; X0:=rh etc. ---------
__global__ __launch_bounds__(512, 1) void k_hop2g(const uch* __restrict__ adjF8,
    const uch* __restrict__ UtFb, const float* __restrict__ XS1,
    const float* __restrict__ X0, const float* __restrict__ X1,
    const float* __restrict__ w_ru, const float* __restrict__ b_ru,
    const float* __restrict__ hx, const float* __restrict__ inp,
    const float* __restrict__ dinv,
    float* __restrict__ X0w, float* __restrict__ XS0w,
    uch* __restrict__ UtFa, float* __restrict__ UG) {
  __shared__ __align__(16) float smem[10240];
  const int bid = blockIdx.x, tid = threadIdx.x;
  const int n0 = bid * 32;
  float sv[5];
  gemm_core2(adjF8, UtFb, bid, tid, smem, sv, ISC2);

  auto xr2 = reinterpret_cast<float(*)[80]>(smem);        // [32][80] = 2560
  float* xr01 = smem + 2560;                              // [2][32][68] = 4352
  float* rhq  = smem + 2560 + 4352;                       // [32][64] = 2048
#pragma unroll
  for (int i = 0; i < 5; ++i) {
    int p = tid + i * 512;
    size_t o = (size_t)n0 * CST + p;
    xr2[p / 80][p % 80] = 2.f * (XS1[o] + sv[i]) - X0[o];
  }
  for (int p = tid; p < 32 * 17; p += 512) {
    int nl = p / 17, c4 = (p % 17) * 4;
    size_t o = (size_t)(n0 + nl) * CST + c4;
    *(float4*)&xr01[nl * 68 + c4]            = *(const float4*)(X0 + o);
    *(float4*)&xr01[32 * 68 + nl * 68 + c4]  = *(const float4*)(X1 + o);
  }
  __syncthreads();

  const int nl = tid >> 4, og = tid & 15, o0 = og * 8;
  float acc[8];
#pragma unroll
  for (int j = 0; j < 8; ++j) acc[j] = b_ru[o0 + j];
  for (int c = 0; c < 66; ++c) {
    int f = (c < 64) ? (c + 2) : (c - 64);
    const float* wr = w_ru + (size_t)(f * 3) * 128 + o0;
    float xv[3];
    xv[0] = xr01[nl * 68 + c];
    xv[1] = xr01[32 * 68 + nl * 68 + c];
    xv[2] = xr2[nl][c];
#pragma unroll
    for (int m = 0; m < 3; ++m) {
      float wl[8];
      *(float4*)(wl)     = *(const float4*)(wr + m * 128);
      *(float4*)(wl + 4) = *(const float4*)(wr + m * 128 + 4);
#pragma unroll
      for (int j = 0; j < 8; ++j) acc[j] += xv[m] * wl[j];
    }
  }
  const int n = n0 + nl;
  const float dv = dinv[n];
  if (og < 8) {
#pragma unroll
    for (int j = 0; j < 8; ++j) {
      int o = o0 + j;
      float r = 1.f / (1.f + expf(-acc[j]));
      float rh = r * hx[n * 64 + o];
      X0w[(size_t)n * CST + o] = rh;
      float srh = dv * rh;
      XS0w[(size_t)n * CST + o] = srh;
      rhq[nl * 64 + o] = srh;
    }
  } else {
#pragma unroll
    for (int j = 0; j < 8; ++j)
      UG[n * 64 + (o0 - 64) + j] = 1.f / (1.f + expf(-acc[j]));
  }
  __syncthreads();
  for (int p = tid; p < 5 * 64; p += 512) {
    int nt = p >> 6, l = p & 63;
    unsigned plo = 0, phi = 0;
#pragma unroll
    for (int j = 0; j < 8; ++j) {
      int lr = 8 * (l >> 4) + j;
      int nn = n0 + lr;
      int c = nt * 16 + (l & 15);
      float v;
      if (c < 64)      v = rhq[lr * 64 + c];
      else if (c < 66) v = dinv[nn] * inp[nn * 2 + (c - 64)];
      else             v = 0.f;
      unsigned b = f2e4m3(v * SC1);
      if (j < 4) plo |= b << (8 * j); else phi |= b << (8 * (j - 4));
    }
    uint2 pk; pk.x = plo; pk.y = phi;
    *(uint2*)(UtFa + ((size_t)(bid >> 1) * 5 + nt) * 1024 + l * 16 + (bid & 1) * 8) = pk;
  }
}

// ---------------- hop2+final: X2 in LDS; tanh matmul; output -----------------
__global__ __launch_bounds__(512, 1) void k_hop2f(const uch* __restrict__ adjF8,
    const uch* __restrict__ UtFb, const float* __restrict__ XS1,
    const float* __restrict__ X0, const float* __restrict__ X1,
    const float* __restrict__ w_c, const float* __restrict__ b_c,
    const float* __restrict__ hx, const float* __restrict__ UG,
    float* __restrict__ out) {
  __shared__ __align__(16) float smem[10240];
  const int bid = blockIdx.x, tid = threadIdx.x;
  const int n0 = bid * 32;
  float sv[5];
  gemm_core2(adjF8, UtFb, bid, tid, smem, sv, ISC2);

  auto xr2 = reinterpret_cast<float(*)[80]>(smem);        // [32][80]
  float* xr01 = smem + 2560;                              // [2][32][68]
#pragma unroll
  for (int i = 0; i < 5; ++i) {
    int p = tid + i * 512;
    size_t o = (size_t)n0 * CST + p;
    xr2[p / 80][p % 80] = 2.f * (XS1[o] + sv[i]) - X0[o];
  }
  for (int p = tid; p < 32 * 17; p += 512) {
    int nl = p / 17, c4 = (p % 17) * 4;
    size_t o = (size_t)(n0 + nl) * CST + c4;
    *(float4*)&xr01[nl * 68 + c4]           = *(const float4*)(X0 + o);
    *(float4*)&xr01[32 * 68 + nl * 68 + c4] = *(const float4*)(X1 + o);
  }
  __syncthreads();

  const int nl = tid >> 4, ot = tid & 15, o0 = ot * 4;
  float acc[4];
#pragma unroll
  for (int j = 0; j < 4; ++j) acc[j] = b_c[o0 + j];
  for (int c = 0; c < 66; ++c) {
    int f = (c < 64) ? (c + 2) : (c - 64);
    float xv[3];
    xv[0] = xr01[nl * 68 + c];
    xv[1] = xr01[32 * 68 + nl * 68 + c];
    xv[2] = xr2[nl][c];
#pragma unroll
    for (int m = 0; m < 3; ++m) {
      float wl[4];
      *(float4*)(wl) = *(const float4*)(w_c + (size_t)(f * 3 + m) * 64 + o0);
#pragma unroll
      for (int j = 0; j < 4; ++j) acc[j] += xv[m] * wl[j];
    }
  }
  const int n = n0 + nl;
#pragma unroll
  for (int j = 0; j < 4; ++j) {
    int o = o0 + j;
    float cc = tanhf(acc[j]);
    float u = UG[n * 64 + o];
    float h = hx[n * 64 + o];
    out[n * 64 + o] = u * h + (1.f - u) * cc;
  }
}

// ---------------- launcher ----------------------------------------------------
extern "C" void kernel_launch(void* const* d_in, const int* in_sizes, int n_in,
                              void* d_out, int out_size, void* d_ws, size_t ws_size,
                              hipStream_t stream) {
  const float* inp  = (const float*)d_in[0];
  const float* hx   = (const float*)d_in[1];
  const float* adj  = (const float*)d_in[2];
  const float* w_ru = (const float*)d_in[3];
  const float* b_ru = (const float*)d_in[4];
  const float* w_c  = (const float*)d_in[5];
  const float* b_c  = (const float*)d_in[6];
  float* out = (float*)d_out;

  float* ws    = (float*)d_ws;
  float* dinv  = ws;                          // 8192
  float* dpart = ws + 8192;                   // 4*8192
  float* X0    = ws + 8192 + 4 * 8192;        // [N][80] each
  float* XS0   = X0 + NS;
  float* X1    = XS0 + NS;
  float* XS1   = X1 + NS;
  uch* UtFa8   = (uch*)(XS1 + NS);            // 640 KB
  uch* UtFb8   = UtFa8 + UTFS8;               // 640 KB
  uch* adjF8   = UtFb8 + UTFS8;               // 64 MB
  float* UG    = (float*)(adjF8 + (size_t)512 * SFT * 1024);  // [N][64] + OOB pad

  dim3 cg(KBT, MCH);

  k_conv <<<cg, 256, 0, stream>>>(adj, adjF8, dpart);
  k_build<<<NN / 32, 256, 0, stream>>>(hx, inp, dpart, dinv, X0, XS0, UtFa8);

  // gconv 1 (gates)
  k_hop1 <<<256, 512, 0, stream>>>(adjF8, UtFa8, XS0, dinv, X1, XS1, UtFb8);
  k_hop2g<<<256, 512, 0, stream>>>(adjF8, UtFb8, XS1, X0, X1, w_ru, b_ru, hx, inp,
                                   dinv, X0, XS0, UtFa8, UG);

  // gconv 2 (candidate)
  k_hop1 <<<256, 512, 0, stream>>>(adjF8, UtFa8, XS0, dinv, X1, XS1, UtFb8);
  k_hop2f<<<256, 512, 0, stream>>>(adjF8, UtFb8, XS1, X0, X1, w_c, b_c, hx, UG, out);
}